// Round 7
// baseline (619.337 us; speedup 1.0000x reference)
//
#include <hip/hip_runtime.h>

// AdaptiveGraphConvolution on MI355X (gfx950)
// out = sum_l m_l * (A_l @ x) @ W_l + bias
//
// R7: feature-sliced gather for L2 residency. x split into 4 slices of 32
// features (3.2 MB each -- fits a 4 MB XCD L2). Pass q: all 4 graphs gather
// against the L2-resident slice (R6: every read was an L2 miss to L3,
// FETCH=198MB/dispatch). Edge record shrunk to u32 {col16|val-bf16}.
// Projection = 4x K=32 GEMM-accumulate into out. Zero global atomics.
// 20 dispatches, ~42.6 MB workspace.

constexpr int N = 50000;
constexpr int E = 800000;
constexpr int D = 128;
constexpr int L = 4;
constexpr int BSH = 4;            // 16 rows per bucket
constexpr int NB = N >> BSH;      // 3125 buckets
constexpr int NCHK = 100;
constexpr int CHUNK = E / NCHK;   // 8000
constexpr int CAP = 1024;         // max bucket size handled by sort2 (max seen ~350)

__device__ inline unsigned bf16rne(unsigned u) {
    return (u + 0x7FFFu + ((u >> 16) & 1u)) >> 16;
}

// ---------------------------------------------------------------------------
// 0) x -> 4 feature-sliced bf16 tables: xb[q][row][fl] packs features
//    (32q+2fl, 32q+2fl+1).  i indexes (row, j=q*16+fl).
// ---------------------------------------------------------------------------
__global__ __launch_bounds__(256) void cvt_x_kernel(
    const float* __restrict__ x, unsigned* __restrict__ xb)
{
    int i = blockIdx.x * 256 + threadIdx.x;     // 0 .. N*64
    int row = i >> 6, j = i & 63;
    int q = j >> 4, fl = j & 15;
    float2 v = *reinterpret_cast<const float2*>(x + (size_t)row * D + q * 32 + fl * 2);
    xb[((size_t)q * N + row) * 16 + fl] =
        bf16rne(__float_as_uint(v.x)) | (bf16rne(__float_as_uint(v.y)) << 16);
}

// ---------------------------------------------------------------------------
// 1) Per-chunk bucket histogram (LDS only), u16 output.
// ---------------------------------------------------------------------------
__global__ __launch_bounds__(256) void bucket_hist_kernel(
    const int* __restrict__ edge_rows, unsigned short* __restrict__ pcnt)
{
    __shared__ int cnt[NB];
    const int blk = blockIdx.x, g = blockIdx.y, tid = threadIdx.x;
    for (int i = tid; i < NB; i += 256) cnt[i] = 0;
    __syncthreads();
    const int* rows = edge_rows + (size_t)g * E + (size_t)blk * CHUNK;
    for (int i = tid; i < CHUNK; i += 256)
        atomicAdd(&cnt[rows[i] >> BSH], 1);
    __syncthreads();
    unsigned short* outp = pcnt + ((size_t)g * NCHK + blk) * NB;
    for (int i = tid; i < NB; i += 256) outp[i] = (unsigned short)cnt[i];
}

// ---------------------------------------------------------------------------
// 2a) Column pass: pcnt -> per-chunk offsets (u16); bucket totals -> bstart.
// ---------------------------------------------------------------------------
__global__ __launch_bounds__(256) void scan1_kernel(
    unsigned short* __restrict__ pcnt, int* __restrict__ bstart)
{
    const int b = blockIdx.x * 256 + threadIdx.x;
    const int g = blockIdx.y;
    if (b >= NB) return;
    unsigned run = 0;
    unsigned short* p = pcnt + (size_t)g * NCHK * NB + b;
    for (int blk = 0; blk < NCHK; ++blk) {
        unsigned v = p[(size_t)blk * NB];
        p[(size_t)blk * NB] = (unsigned short)run;
        run += v;
    }
    bstart[(size_t)g * (NB + 1) + b] = (int)run;
}

// ---------------------------------------------------------------------------
// 2b) Per-graph exclusive scan of bucket totals.
// ---------------------------------------------------------------------------
__global__ __launch_bounds__(1024) void scan2_kernel(int* __restrict__ bstart)
{
    __shared__ int sums[1024];
    int* bs = bstart + (size_t)blockIdx.x * (NB + 1);
    const int t = threadIdx.x;
    int tv[4];
    int s = 0;
#pragma unroll
    for (int i = 0; i < 4; ++i) {
        int idx = t * 4 + i;
        tv[i] = (idx < NB) ? bs[idx] : 0;
        s += tv[i];
    }
    sums[t] = s;
    __syncthreads();
    for (int off = 1; off < 1024; off <<= 1) {
        int v = (t >= off) ? sums[t - off] : 0;
        __syncthreads();
        sums[t] += v;
        __syncthreads();
    }
    int ex = (t == 0) ? 0 : sums[t - 1];
#pragma unroll
    for (int i = 0; i < 4; ++i) {
        int idx = t * 4 + i;
        if (idx < NB) { bs[idx] = ex; ex += tv[i]; }
    }
    if (t == 0) bs[NB] = E;
}

// ---------------------------------------------------------------------------
// 3) Fill (per graph): bucket-ordered cv = col | bf16(val)<<16, plus rl8
//    (row-in-bucket, for sort2's key). No global atomics.
// ---------------------------------------------------------------------------
__global__ __launch_bounds__(256) void fill_kernel(
    const int* __restrict__ rows_g,
    const int* __restrict__ cols_g,
    const float* __restrict__ vals_g,
    const unsigned short* __restrict__ pcnt_g,   // [NCHK][NB]
    const int* __restrict__ bstart_g,            // [NB+1]
    unsigned* __restrict__ cv_g,                 // [E]
    unsigned char* __restrict__ rl8)             // [E]
{
    __shared__ int base[NB];
    __shared__ int cur[NB];
    const int blk = blockIdx.x, tid = threadIdx.x;
    const unsigned short* pc = pcnt_g + (size_t)blk * NB;
    for (int i = tid; i < NB; i += 256) {
        base[i] = bstart_g[i] + (int)pc[i];
        cur[i] = 0;
    }
    __syncthreads();
    const int* rows = rows_g + (size_t)blk * CHUNK;
    const int* cols = cols_g + (size_t)blk * CHUNK;
    const float* vals = vals_g + (size_t)blk * CHUNK;
    for (int i = tid; i < CHUNK; i += 256) {
        int r = rows[i];
        int b = r >> BSH;
        int rank = atomicAdd(&cur[b], 1);
        int pos = base[b] + rank;
        cv_g[pos] = (unsigned)cols[i] |
                    (bf16rne(__float_as_uint(vals[i])) << 16);
        rl8[pos] = (unsigned char)(r & 15);
    }
}

// ---------------------------------------------------------------------------
// 4) sort2 (per graph): per-bucket LDS counting sort by rl8 (cv in place),
//    emits CSR rowptr.
// ---------------------------------------------------------------------------
__global__ __launch_bounds__(256) void sort2_kernel(
    unsigned* __restrict__ cv_g,
    const unsigned char* __restrict__ rl8,
    const int* __restrict__ bstart_g,
    int* __restrict__ rowptr_g)
{
    __shared__ unsigned scv[CAP];
    __shared__ unsigned char srl[CAP];
    __shared__ int rc[17], rcur[16];
    const int b = blockIdx.x, tid = threadIdx.x;
    const int beg = bstart_g[b];
    const int end = bstart_g[b + 1];
    int cnt = end - beg;
    if (cnt > CAP) cnt = CAP;   // unreachable for this data (112 sigma)
    if (b == 0 && tid == 0) rowptr_g[N] = E;
    if (tid < 17) rc[tid] = 0;
    __syncthreads();
    for (int i = tid; i < cnt; i += 256) {
        scv[i] = cv_g[beg + i];
        int rl = rl8[beg + i];
        srl[i] = (unsigned char)rl;
        atomicAdd(&rc[rl + 1], 1);
    }
    __syncthreads();
    if (tid == 0) {
        int run = 0;
#pragma unroll
        for (int r = 1; r <= 16; ++r) { run += rc[r]; rc[r] = run; }
    }
    __syncthreads();
    if (tid < 16) {
        rcur[tid] = rc[tid];
        rowptr_g[b * 16 + tid] = beg + rc[tid];
    }
    __syncthreads();
    for (int i = tid; i < cnt; i += 256) {
        int p = atomicAdd(&rcur[srl[i]], 1);
        cv_g[beg + p] = scv[i];
    }
}

// ---------------------------------------------------------------------------
// 5) Sliced gather: pass q, grid (N/4, L). Wave = row; quarter-wave = one
//    edge's 64B slice read from the L2-resident xb_q; shfl_xor folds the 4
//    partial accs. Writes y[l][row][16] packed bf16.
// ---------------------------------------------------------------------------
__global__ __launch_bounds__(256) void gather_kernel(
    const unsigned* __restrict__ xb,      // [4][N][16]
    const unsigned* __restrict__ cv,      // [L][E]
    const int* __restrict__ rowptr,       // [L][N+1]
    unsigned* __restrict__ y,             // [L][N][16]
    int q)
{
    const int tid = threadIdx.x;
    const int row = blockIdx.x * 4 + (tid >> 6);
    const int l = blockIdx.y;
    const int lane = tid & 63;
    const int sub = lane >> 4, fl = lane & 15;

    const unsigned* xq = xb + (size_t)q * N * 16;
    const unsigned* cvg = cv + (size_t)l * E;
    const int* rp = rowptr + (size_t)l * (N + 1);

    const int beg = rp[row], end = rp[row + 1];
    float accx = 0.f, accy = 0.f;
    for (int j = beg; j < end; j += 4) {
        int idx = j + sub;
        unsigned c = (idx < end) ? cvg[idx] : 0u;   // 16B wave fetch, qtr-bcast
        float v = __uint_as_float(c & 0xFFFF0000u);
        unsigned col = c & 0xFFFFu;
        unsigned xv = xq[(size_t)col * 16 + fl];    // 64B granule per quarter
        accx = fmaf(v, __uint_as_float(xv << 16), accx);
        accy = fmaf(v, __uint_as_float(xv & 0xFFFF0000u), accy);
    }
    accx += __shfl_xor(accx, 16); accx += __shfl_xor(accx, 32);
    accy += __shfl_xor(accy, 16); accy += __shfl_xor(accy, 32);
    if (lane < 16)
        y[((size_t)l * N + row) * 16 + fl] =
            bf16rne(__float_as_uint(accx)) | (bf16rne(__float_as_uint(accy)) << 16);
}

// ---------------------------------------------------------------------------
// 6) K=32 GEMM-accumulate, pass q:
//    out[n][f] (+)= sum_l sum_{d in slice q} y_l[n][d] * (m_l W_l[d][f])
//    q==0 initializes from bias; q>0 reads out back. Block = 32 rows.
// ---------------------------------------------------------------------------
__global__ __launch_bounds__(256) void gemm_kernel(
    const unsigned* __restrict__ y,      // [L][N][16]
    const float* __restrict__ W,         // [L][D][D]
    const float* __restrict__ mix,
    const float* __restrict__ bias,
    float* __restrict__ out,
    int q)
{
    __shared__ float lw[32][D];   // 16 KB
    __shared__ float ly[32][32];  // 4 KB

    const int tid = threadIdx.x;
    const int lane = tid & 63, wave = tid >> 6;
    const int r0 = blockIdx.x * 32;
    const int f0 = 2 * lane;
    const int wr = wave * 8;

    float2 acc[8];
#pragma unroll
    for (int r = 0; r < 8; ++r) {
        int row = r0 + wr + r;
        if (q == 0) {
            acc[r].x = bias[f0];
            acc[r].y = bias[f0 + 1];
        } else if (row < N) {
            acc[r] = *reinterpret_cast<const float2*>(out + (size_t)row * D + f0);
        } else {
            acc[r] = make_float2(0.f, 0.f);
        }
    }

    for (int l = 0; l < L; ++l) {
        const float m = mix[l];
        {   // stage W slice [32][128] * m
            const float4* ws = reinterpret_cast<const float4*>(
                W + (size_t)l * D * D + (size_t)q * 32 * D);
#pragma unroll
            for (int i = 0; i < 4; ++i) {
                int idx = i * 256 + tid;
                float4 w = ws[idx];
                reinterpret_cast<float4*>(lw)[idx] =
                    make_float4(m * w.x, m * w.y, m * w.z, m * w.w);
            }
        }
        {   // stage y tile [32][32] f32 from packed bf16
            int rl = tid >> 3, j2 = tid & 7;
            int row = r0 + rl;
            uint2 p = make_uint2(0u, 0u);
            if (row < N)
                p = *reinterpret_cast<const uint2*>(
                    y + ((size_t)l * N + row) * 16 + j2 * 2);
            float* dst = &ly[rl][j2 * 4];
            dst[0] = __uint_as_float(p.x << 16);
            dst[1] = __uint_as_float(p.x & 0xFFFF0000u);
            dst[2] = __uint_as_float(p.y << 16);
            dst[3] = __uint_as_float(p.y & 0xFFFF0000u);
        }
        __syncthreads();
#pragma unroll
        for (int d = 0; d < 32; ++d) {
            float2 wv = *reinterpret_cast<const float2*>(&lw[d][f0]);
#pragma unroll
            for (int r = 0; r < 8; ++r) {
                float ys = ly[wr + r][d];
                acc[r].x = fmaf(ys, wv.x, acc[r].x);
                acc[r].y = fmaf(ys, wv.y, acc[r].y);
            }
        }
        __syncthreads();
    }

#pragma unroll
    for (int r = 0; r < 8; ++r) {
        int row = r0 + wr + r;
        if (row < N)
            *reinterpret_cast<float2*>(out + (size_t)row * D + f0) = acc[r];
    }
}

extern "C" void kernel_launch(void* const* d_in, const int* in_sizes, int n_in,
                              void* d_out, int out_size, void* d_ws, size_t ws_size,
                              hipStream_t stream)
{
    const float* x         = (const float*)d_in[0];
    const int*   edge_rows = (const int*)d_in[1];
    const int*   edge_cols = (const int*)d_in[2];
    const float* edge_vals = (const float*)d_in[3];
    const float* W         = (const float*)d_in[4];
    const float* mix       = (const float*)d_in[5];
    const float* bias      = (const float*)d_in[6];
    float* out = (float*)d_out;

    // Workspace (~42.6 MB):
    // cv [L][E] u32 | pcnt [L][NCHK][NB] u16 | bstart [L][NB+1] |
    // rowptr [L][N+1] | xb [4][N][16] u32 | y [L][N][16] u32 | rl8 [E] u8
    unsigned*       cv     = (unsigned*)d_ws;
    unsigned short* pcnt   = (unsigned short*)(cv + (size_t)L * E);
    int*            bstart = (int*)(pcnt + (size_t)L * NCHK * NB);
    int*            rowptr = bstart + (size_t)L * (NB + 1);
    unsigned*       xb     = (unsigned*)(rowptr + (size_t)L * (N + 1));
    unsigned*       y      = xb + (size_t)4 * N * 16;
    unsigned char*  rl8    = (unsigned char*)(y + (size_t)L * N * 16);

    cvt_x_kernel<<<(N * 64) / 256, 256, 0, stream>>>(x, xb);
    bucket_hist_kernel<<<dim3(NCHK, L), 256, 0, stream>>>(edge_rows, pcnt);
    scan1_kernel<<<dim3((NB + 255) / 256, L), 256, 0, stream>>>(pcnt, bstart);
    scan2_kernel<<<L, 1024, 0, stream>>>(bstart);

    for (int l = 0; l < L; ++l) {
        fill_kernel<<<NCHK, 256, 0, stream>>>(
            edge_rows + (size_t)l * E,
            edge_cols + (size_t)l * E,
            edge_vals + (size_t)l * E,
            pcnt + (size_t)l * NCHK * NB,
            bstart + (size_t)l * (NB + 1),
            cv + (size_t)l * E,
            rl8);
        sort2_kernel<<<NB, 256, 0, stream>>>(
            cv + (size_t)l * E,
            rl8,
            bstart + (size_t)l * (NB + 1),
            rowptr + (size_t)l * (N + 1));
    }

    for (int q = 0; q < 4; ++q) {
        gather_kernel<<<dim3(N / 4, L), 256, 0, stream>>>(xb, cv, rowptr, y, q);
        gemm_kernel<<<(N + 31) / 32, 256, 0, stream>>>(y, W, mix, bias, out, q);
    }
}

// Round 8
// 524.139 us; speedup vs baseline: 1.1816x; 1.1816x over previous
//
#include <hip/hip_runtime.h>

// AdaptiveGraphConvolution on MI355X (gfx950)
// out = sum_l m_l * (A_l @ x) @ W_l + bias
//
// R8: L2-resident sliced gather (R7's 3.2MB x-slice tables, FETCH 198->29MB)
// combined with R6's decoupled load structure (batch-preload 64 edges' cv,
// shfl-broadcast cols -> all xb loads address-independent, branch-free
// padding). Build phase merged across graphs (fill/sort2 one launch each).
// 14 dispatches, ~44.3 MB workspace, zero global atomics.

constexpr int N = 50000;
constexpr int E = 800000;
constexpr int D = 128;
constexpr int L = 4;
constexpr int BSH = 4;            // 16 rows per bucket
constexpr int NB = N >> BSH;      // 3125 buckets
constexpr int NCHK = 100;
constexpr int CHUNK = E / NCHK;   // 8000
constexpr int CAP = 1024;         // max bucket size in sort2 (mean 256, +48 sigma)

__device__ inline unsigned bf16rne(unsigned u) {
    return (u + 0x7FFFu + ((u >> 16) & 1u)) >> 16;
}

// ---------------------------------------------------------------------------
// 0) x -> 4 feature-sliced bf16 tables: xb[q][row][fl] packs features
//    (32q+2fl, 32q+2fl+1).
// ---------------------------------------------------------------------------
__global__ __launch_bounds__(256) void cvt_x_kernel(
    const float* __restrict__ x, unsigned* __restrict__ xb)
{
    int i = blockIdx.x * 256 + threadIdx.x;     // 0 .. N*64
    int row = i >> 6, j = i & 63;
    int q = j >> 4, fl = j & 15;
    float2 v = *reinterpret_cast<const float2*>(x + (size_t)row * D + q * 32 + fl * 2);
    xb[((size_t)q * N + row) * 16 + fl] =
        bf16rne(__float_as_uint(v.x)) | (bf16rne(__float_as_uint(v.y)) << 16);
}

// ---------------------------------------------------------------------------
// 1) Per-chunk bucket histogram (LDS only), u16 output.
// ---------------------------------------------------------------------------
__global__ __launch_bounds__(256) void bucket_hist_kernel(
    const int* __restrict__ edge_rows, unsigned short* __restrict__ pcnt)
{
    __shared__ int cnt[NB];
    const int blk = blockIdx.x, g = blockIdx.y, tid = threadIdx.x;
    for (int i = tid; i < NB; i += 256) cnt[i] = 0;
    __syncthreads();
    const int* rows = edge_rows + (size_t)g * E + (size_t)blk * CHUNK;
    for (int i = tid; i < CHUNK; i += 256)
        atomicAdd(&cnt[rows[i] >> BSH], 1);
    __syncthreads();
    unsigned short* outp = pcnt + ((size_t)g * NCHK + blk) * NB;
    for (int i = tid; i < NB; i += 256) outp[i] = (unsigned short)cnt[i];
}

// ---------------------------------------------------------------------------
// 2a) Column pass: pcnt -> per-chunk offsets (u16); bucket totals -> bstart.
// ---------------------------------------------------------------------------
__global__ __launch_bounds__(256) void scan1_kernel(
    unsigned short* __restrict__ pcnt, int* __restrict__ bstart)
{
    const int b = blockIdx.x * 256 + threadIdx.x;
    const int g = blockIdx.y;
    if (b >= NB) return;
    unsigned run = 0;
    unsigned short* p = pcnt + (size_t)g * NCHK * NB + b;
    for (int blk = 0; blk < NCHK; ++blk) {
        unsigned v = p[(size_t)blk * NB];
        p[(size_t)blk * NB] = (unsigned short)run;
        run += v;
    }
    bstart[(size_t)g * (NB + 1) + b] = (int)run;
}

// ---------------------------------------------------------------------------
// 2b) Per-graph exclusive scan of bucket totals.
// ---------------------------------------------------------------------------
__global__ __launch_bounds__(1024) void scan2_kernel(int* __restrict__ bstart)
{
    __shared__ int sums[1024];
    int* bs = bstart + (size_t)blockIdx.x * (NB + 1);
    const int t = threadIdx.x;
    int tv[4];
    int s = 0;
#pragma unroll
    for (int i = 0; i < 4; ++i) {
        int idx = t * 4 + i;
        tv[i] = (idx < NB) ? bs[idx] : 0;
        s += tv[i];
    }
    sums[t] = s;
    __syncthreads();
    for (int off = 1; off < 1024; off <<= 1) {
        int v = (t >= off) ? sums[t - off] : 0;
        __syncthreads();
        sums[t] += v;
        __syncthreads();
    }
    int ex = (t == 0) ? 0 : sums[t - 1];
#pragma unroll
    for (int i = 0; i < 4; ++i) {
        int idx = t * 4 + i;
        if (idx < NB) { bs[idx] = ex; ex += tv[i]; }
    }
    if (t == 0) bs[NB] = E;
}

// ---------------------------------------------------------------------------
// 3) Fill, all graphs (grid NCHK x L): bucket-ordered cv = col | bf16(val)<<16
//    plus rl8 key. No global atomics.
// ---------------------------------------------------------------------------
__global__ __launch_bounds__(256) void fill_kernel(
    const int* __restrict__ edge_rows,
    const int* __restrict__ edge_cols,
    const float* __restrict__ edge_vals,
    const unsigned short* __restrict__ pcnt,     // [L][NCHK][NB]
    const int* __restrict__ bstart,              // [L][NB+1]
    unsigned* __restrict__ cv,                   // [L][E]
    unsigned char* __restrict__ rl8)             // [L][E]
{
    __shared__ int base[NB];
    __shared__ int cur[NB];
    const int blk = blockIdx.x, g = blockIdx.y, tid = threadIdx.x;
    const unsigned short* pc = pcnt + ((size_t)g * NCHK + blk) * NB;
    const int* bs = bstart + (size_t)g * (NB + 1);
    for (int i = tid; i < NB; i += 256) {
        base[i] = bs[i] + (int)pc[i];
        cur[i] = 0;
    }
    __syncthreads();
    const size_t eoff = (size_t)g * E + (size_t)blk * CHUNK;
    const int* rows = edge_rows + eoff;
    const int* cols = edge_cols + eoff;
    const float* vals = edge_vals + eoff;
    unsigned* cvg = cv + (size_t)g * E;
    unsigned char* rlg = rl8 + (size_t)g * E;
    for (int i = tid; i < CHUNK; i += 256) {
        int r = rows[i];
        int b = r >> BSH;
        int rank = atomicAdd(&cur[b], 1);
        int pos = base[b] + rank;
        cvg[pos] = (unsigned)cols[i] | (bf16rne(__float_as_uint(vals[i])) << 16);
        rlg[pos] = (unsigned char)(r & 15);
    }
}

// ---------------------------------------------------------------------------
// 4) sort2, all graphs (grid NB x L): per-bucket LDS counting sort by rl8
//    (cv in place), emits CSR rowptr.
// ---------------------------------------------------------------------------
__global__ __launch_bounds__(256) void sort2_kernel(
    unsigned* __restrict__ cv,
    const unsigned char* __restrict__ rl8,
    const int* __restrict__ bstart,
    int* __restrict__ rowptr)
{
    __shared__ unsigned scv[CAP];
    __shared__ unsigned char srl[CAP];
    __shared__ int rc[17], rcur[16];
    const int b = blockIdx.x, g = blockIdx.y, tid = threadIdx.x;
    const int beg = bstart[(size_t)g * (NB + 1) + b];
    const int end = bstart[(size_t)g * (NB + 1) + b + 1];
    unsigned* cvg = cv + (size_t)g * E;
    const unsigned char* rlg = rl8 + (size_t)g * E;
    int* rp = rowptr + (size_t)g * (N + 1);
    int cnt = end - beg;
    if (cnt > CAP) cnt = CAP;   // unreachable for this data
    if (b == 0 && tid == 0) rp[N] = E;
    if (tid < 17) rc[tid] = 0;
    __syncthreads();
    for (int i = tid; i < cnt; i += 256) {
        scv[i] = cvg[beg + i];
        int rl = rlg[beg + i];
        srl[i] = (unsigned char)rl;
        atomicAdd(&rc[rl + 1], 1);
    }
    __syncthreads();
    if (tid == 0) {
        int run = 0;
#pragma unroll
        for (int r = 1; r <= 16; ++r) { run += rc[r]; rc[r] = run; }
    }
    __syncthreads();
    if (tid < 16) {
        rcur[tid] = rc[tid];
        rp[b * 16 + tid] = beg + rc[tid];
    }
    __syncthreads();
    for (int i = tid; i < cnt; i += 256) {
        int p = atomicAdd(&rcur[srl[i]], 1);
        cvg[beg + p] = scv[i];
    }
}

// ---------------------------------------------------------------------------
// 5) Sliced gather, pass q, grid (N/4, L). Wave = row. Batch-preload up to
//    64 edges' cv (one coalesced 256B read; lanes >= cnt zeroed -> padding
//    edges have v=+0, branch-free). Inner loop: shfl-broadcast cv to the
//    quarter-wave -> 64B xq read (L2-resident slice) -> 2 fma. All xq loads
//    address-independent. shfl_xor folds quarters; lane<16 writes y bf16.
// ---------------------------------------------------------------------------
__global__ __launch_bounds__(256) void gather_kernel(
    const unsigned* __restrict__ xb,      // [4][N][16]
    const unsigned* __restrict__ cv,      // [L][E]
    const int* __restrict__ rowptr,       // [L][N+1]
    unsigned* __restrict__ y,             // [L][N][16]
    int q)
{
    const int tid = threadIdx.x;
    const int row = blockIdx.x * 4 + (tid >> 6);
    const int l = blockIdx.y;
    const int lane = tid & 63;
    const int sub = lane >> 4, fl = lane & 15;

    const unsigned* xq = xb + (size_t)q * N * 16;
    const unsigned* cvg = cv + (size_t)l * E;
    const int* rp = rowptr + (size_t)l * (N + 1);

    const int beg = rp[row], end = rp[row + 1];
    float accx = 0.f, accy = 0.f;
    for (int base = beg; base < end; base += 64) {
        int cnt = end - base;
        if (cnt > 64) cnt = 64;
        unsigned cvr = (lane < cnt) ? cvg[base + lane] : 0u;
        const int nk = (cnt + 3) >> 2;
#pragma unroll 4
        for (int k = 0; k < nk; ++k) {
            unsigned c = __shfl(cvr, k * 4 + sub);
            float v = __uint_as_float(c & 0xFFFF0000u);   // padding -> +0.0
            unsigned col = c & 0xFFFFu;
            unsigned xv = xq[(size_t)col * 16 + fl];
            accx = fmaf(v, __uint_as_float(xv << 16), accx);
            accy = fmaf(v, __uint_as_float(xv & 0xFFFF0000u), accy);
        }
    }
    accx += __shfl_xor(accx, 16); accx += __shfl_xor(accx, 32);
    accy += __shfl_xor(accy, 16); accy += __shfl_xor(accy, 32);
    if (lane < 16)
        y[((size_t)l * N + row) * 16 + fl] =
            bf16rne(__float_as_uint(accx)) | (bf16rne(__float_as_uint(accy)) << 16);
}

// ---------------------------------------------------------------------------
// 6) K=32 GEMM-accumulate, pass q:
//    out[n][f] (+)= sum_l sum_{d in slice q} y_l[n][d] * (m_l W_l[d][f])
// ---------------------------------------------------------------------------
__global__ __launch_bounds__(256) void gemm_kernel(
    const unsigned* __restrict__ y,      // [L][N][16]
    const float* __restrict__ W,         // [L][D][D]
    const float* __restrict__ mix,
    const float* __restrict__ bias,
    float* __restrict__ out,
    int q)
{
    __shared__ float lw[32][D];   // 16 KB
    __shared__ float ly[32][32];  // 4 KB

    const int tid = threadIdx.x;
    const int lane = tid & 63, wave = tid >> 6;
    const int r0 = blockIdx.x * 32;
    const int f0 = 2 * lane;
    const int wr = wave * 8;

    float2 acc[8];
#pragma unroll
    for (int r = 0; r < 8; ++r) {
        int row = r0 + wr + r;
        if (q == 0) {
            acc[r].x = bias[f0];
            acc[r].y = bias[f0 + 1];
        } else if (row < N) {
            acc[r] = *reinterpret_cast<const float2*>(out + (size_t)row * D + f0);
        } else {
            acc[r] = make_float2(0.f, 0.f);
        }
    }

    for (int l = 0; l < L; ++l) {
        const float m = mix[l];
        {   // stage W slice [32][128] * m
            const float4* ws = reinterpret_cast<const float4*>(
                W + (size_t)l * D * D + (size_t)q * 32 * D);
#pragma unroll
            for (int i = 0; i < 4; ++i) {
                int idx = i * 256 + tid;
                float4 w = ws[idx];
                reinterpret_cast<float4*>(lw)[idx] =
                    make_float4(m * w.x, m * w.y, m * w.z, m * w.w);
            }
        }
        {   // stage y tile [32][32] f32 from packed bf16
            int rl = tid >> 3, j2 = tid & 7;
            int row = r0 + rl;
            uint2 p = make_uint2(0u, 0u);
            if (row < N)
                p = *reinterpret_cast<const uint2*>(
                    y + ((size_t)l * N + row) * 16 + j2 * 2);
            float* dst = &ly[rl][j2 * 4];
            dst[0] = __uint_as_float(p.x << 16);
            dst[1] = __uint_as_float(p.x & 0xFFFF0000u);
            dst[2] = __uint_as_float(p.y << 16);
            dst[3] = __uint_as_float(p.y & 0xFFFF0000u);
        }
        __syncthreads();
#pragma unroll
        for (int d = 0; d < 32; ++d) {
            float2 wv = *reinterpret_cast<const float2*>(&lw[d][f0]);
#pragma unroll
            for (int r = 0; r < 8; ++r) {
                float ys = ly[wr + r][d];
                acc[r].x = fmaf(ys, wv.x, acc[r].x);
                acc[r].y = fmaf(ys, wv.y, acc[r].y);
            }
        }
        __syncthreads();
    }

#pragma unroll
    for (int r = 0; r < 8; ++r) {
        int row = r0 + wr + r;
        if (row < N)
            *reinterpret_cast<float2*>(out + (size_t)row * D + f0) = acc[r];
    }
}

extern "C" void kernel_launch(void* const* d_in, const int* in_sizes, int n_in,
                              void* d_out, int out_size, void* d_ws, size_t ws_size,
                              hipStream_t stream)
{
    const float* x         = (const float*)d_in[0];
    const int*   edge_rows = (const int*)d_in[1];
    const int*   edge_cols = (const int*)d_in[2];
    const float* edge_vals = (const float*)d_in[3];
    const float* W         = (const float*)d_in[4];
    const float* mix       = (const float*)d_in[5];
    const float* bias      = (const float*)d_in[6];
    float* out = (float*)d_out;

    // Workspace (~44.3 MB):
    // cv [L][E] u32 (12.8M) | pcnt [L][NCHK][NB] u16 (2.5M) | bstart | rowptr |
    // xb [4][N][16] u32 (12.8M) | y [L][N][16] u32 (12.8M) | rl8 [L][E] u8 (3.2M)
    unsigned*       cv     = (unsigned*)d_ws;
    unsigned short* pcnt   = (unsigned short*)(cv + (size_t)L * E);
    int*            bstart = (int*)(pcnt + (size_t)L * NCHK * NB);
    int*            rowptr = bstart + (size_t)L * (NB + 1);
    unsigned*       xb     = (unsigned*)(rowptr + (size_t)L * (N + 1));
    unsigned*       y      = xb + (size_t)4 * N * 16;
    unsigned char*  rl8    = (unsigned char*)(y + (size_t)L * N * 16);

    cvt_x_kernel<<<(N * 64) / 256, 256, 0, stream>>>(x, xb);
    bucket_hist_kernel<<<dim3(NCHK, L), 256, 0, stream>>>(edge_rows, pcnt);
    scan1_kernel<<<dim3((NB + 255) / 256, L), 256, 0, stream>>>(pcnt, bstart);
    scan2_kernel<<<L, 1024, 0, stream>>>(bstart);
    fill_kernel<<<dim3(NCHK, L), 256, 0, stream>>>(edge_rows, edge_cols, edge_vals,
                                                   pcnt, bstart, cv, rl8);
    sort2_kernel<<<dim3(NB, L), 256, 0, stream>>>(cv, rl8, bstart, rowptr);

    for (int q = 0; q < 4; ++q) {
        gather_kernel<<<dim3(N / 4, L), 256, 0, stream>>>(xb, cv, rowptr, y, q);
        gemm_kernel<<<(N + 31) / 32, 256, 0, stream>>>(y, W, mix, bias, out, q);
    }
}